// Round 8
// baseline (78.840 us; speedup 1.0000x reference)
//
#include <hip/hip_runtime.h>

// 5-level wavedec (filter len 8, pywt 'symmetric'), 4096 rows of 8192 f32.
// Lengths: 8192 -> 4099 -> 2053 -> 1030 -> 518 -> 262
// Out: approx(262) @0, d5(262), d4(518), d3(1030), d2(2053), d1(4099).
//
// R8: fuse L1+L2 through registers + wave shuffles. a1 never touches LDS:
// each thread computes a1[4j..4j+3] in regs (same 16-float window as d1),
// gets a1[4j-6..4j-1] from lanes l-1/l-2 via __shfl_up, and emits
// a2[2j],a2[2j+1] (LDS) + d2 (global). LDS = a2(2056)+a3(1032) = 12.4 KB
// -> 8 blocks/CU (32 waves, 100% theoretical occupancy), 3 barriers not 5.

static constexpr int ROWS = 4096;
static constexpr int N0 = 8192;
static constexpr int L1n = 4099, L2n = 2053, L3n = 1030, L4n = 518, L5n = 262;
static constexpr size_t OFF_D5 = 1073152u;
static constexpr size_t OFF_D4 = 2146304u;
static constexpr size_t OFF_D3 = 4268032u;
static constexpr size_t OFF_D2 = 8486912u;
static constexpr size_t OFF_D1 = 16896000u;

__device__ __forceinline__ float refl_load(const float* __restrict__ s, int idx, int n) {
    int i = (idx < 0) ? (-1 - idx) : ((idx >= n) ? (2 * n - 1 - idx) : idx);
    return s[i];
}

// a1[i] honestly from x (with x-reflection), 8 FMA
__device__ __forceinline__ float a1_val(const float* __restrict__ xr, int i,
                                        const float* __restrict__ h) {
    float a = 0.f;
#pragma unroll
    for (int q = 0; q < 8; ++q)
        a = fmaf(h[q], refl_load(xr, 2 * i + 1 - q, N0), a);
    return a;
}

// R3-proven generic level for L3/L4/L5 (LDS src, 4 outputs/thread)
__device__ __forceinline__ void dwt_level(
    const float* __restrict__ src, int n, int m,
    const float* __restrict__ h, const float* __restrict__ g,
    float* __restrict__ adst, float* __restrict__ ddst, int tid)
{
    const int ngroups = (m + 3) >> 2;
    const int jmax = (n - 10) >> 3;
    for (int j = tid; j < ngroups; j += 256) {
        const int p0 = 4 * j;
        if (j >= 1 && j <= jmax && p0 + 3 < m) {
            const float2* __restrict__ s2 =
                reinterpret_cast<const float2*>(src) + (4 * j - 3);
            float w[16];
#pragma unroll
            for (int t = 0; t < 8; ++t) {
                const float2 v = s2[t];
                w[2 * t] = v.x; w[2 * t + 1] = v.y;
            }
#pragma unroll
            for (int r = 0; r < 4; ++r) {
                float a = 0.f, d = 0.f;
#pragma unroll
                for (int q = 0; q < 8; ++q) {
                    const float v = w[2 * r + 7 - q];
                    a = fmaf(h[q], v, a);
                    d = fmaf(g[q], v, d);
                }
                ddst[p0 + r] = d;
                adst[p0 + r] = a;
            }
        } else {
#pragma unroll 4
            for (int r = 0; r < 4; ++r) {
                const int pos = p0 + r;
                if (pos >= m) break;
                const int s0 = 2 * pos + 1;
                float a = 0.f, d = 0.f;
#pragma unroll
                for (int q = 0; q < 8; ++q) {
                    const float v = refl_load(src, s0 - q, n);
                    a = fmaf(h[q], v, a);
                    d = fmaf(g[q], v, d);
                }
                ddst[pos] = d;
                adst[pos] = a;
            }
        }
    }
}

__global__ __launch_bounds__(256, 8)
void wavedec5_fused(const float* __restrict__ x,
                    const float* __restrict__ dlo,
                    const float* __restrict__ dhi,
                    float* __restrict__ out)
{
    __shared__ __align__(16) float a2buf[2056];   // a2 (2053), later a4 (518)
    __shared__ __align__(16) float a3buf[1032];   // a3 (1030)

    const int tid  = threadIdx.x;
    const int lane = tid & 63;
    const int row  = blockIdx.x;

    float h[8], g[8];
#pragma unroll
    for (int i = 0; i < 8; ++i) { h[i] = dlo[i]; g[i] = dhi[i]; }

    const float* __restrict__ xr = x + (size_t)row * N0;
    float* __restrict__ d1out = out + OFF_D1 + (size_t)row * L1n;
    float* __restrict__ d2out = out + OFF_D2 + (size_t)row * L2n;

    // ---- fused L1+L2 main loop: j in [3,1022], lane-consecutive ----
    for (int j = 3 + tid; j <= 1022; j += 256) {
        // 16-float x window [8j-6 .. 8j+9] (interior: j<=1022 -> max idx 8185)
        const float2* __restrict__ s2 =
            reinterpret_cast<const float2*>(xr) + (4 * j - 3);
        float w[16];
#pragma unroll
        for (int t = 0; t < 8; ++t) {
            const float2 v = s2[t];
            w[2 * t] = v.x; w[2 * t + 1] = v.y;
        }
        float a1o[4], dd[4];
#pragma unroll
        for (int r = 0; r < 4; ++r) {
            float a = 0.f, d = 0.f;
#pragma unroll
            for (int q = 0; q < 8; ++q) {
                const float v = w[2 * r + 7 - q];   // x[2(4j+r)+1-q]
                a = fmaf(h[q], v, a);
                d = fmaf(g[q], v, d);
            }
            a1o[r] = a; dd[r] = d;
        }
#pragma unroll
        for (int r = 0; r < 4; ++r) d1out[4 * j + r] = dd[r];

        // gather a1[4j-6 .. 4j-1] from lanes l-2, l-1
        float v0 = __shfl_up(a1o[2], 2, 64);   // a1[4j-6]
        float v1 = __shfl_up(a1o[3], 2, 64);   // a1[4j-5]
        float v2 = __shfl_up(a1o[0], 1, 64);   // a1[4j-4]
        float v3 = __shfl_up(a1o[1], 1, 64);   // a1[4j-3]
        float v4 = __shfl_up(a1o[2], 1, 64);   // a1[4j-2]
        float v5 = __shfl_up(a1o[3], 1, 64);   // a1[4j-1]
        if (lane < 2) {                        // wave seam: recompute honestly
            v0 = a1_val(xr, 4 * j - 6, h);
            v1 = a1_val(xr, 4 * j - 5, h);
            v2 = a1_val(xr, 4 * j - 4, h);
            v3 = a1_val(xr, 4 * j - 3, h);
            v4 = a1_val(xr, 4 * j - 2, h);
            v5 = a1_val(xr, 4 * j - 1, h);
        }
        float v[10] = {v0, v1, v2, v3, v4, v5, a1o[0], a1o[1], a1o[2], a1o[3]};
        // a2[p]=sum h[q]*a1[2p+1-q]: p=2j -> v[7-q]; p=2j+1 -> v[9-q]
        float a20 = 0.f, d20 = 0.f, a21 = 0.f, d21 = 0.f;
#pragma unroll
        for (int q = 0; q < 8; ++q) {
            a20 = fmaf(h[q], v[7 - q], a20);
            d20 = fmaf(g[q], v[7 - q], d20);
            a21 = fmaf(h[q], v[9 - q], a21);
            d21 = fmaf(g[q], v[9 - q], d21);
        }
        a2buf[2 * j]     = a20;
        a2buf[2 * j + 1] = a21;
        d2out[2 * j]     = d20;
        d2out[2 * j + 1] = d21;
    }

    // ---- edges ----
    if (tid < 13) {
        // a2/d2 positions {0..5, 2046..2052} with a1-level reflection
        const int p = (tid < 6) ? tid : (2040 + tid);
        float a2v = 0.f, d2v = 0.f;
#pragma unroll
        for (int q = 0; q < 8; ++q) {
            int s = 2 * p + 1 - q;
            int si = (s < 0) ? (-1 - s) : ((s >= L1n) ? (2 * L1n - 1 - s) : s);
            const float av = a1_val(xr, si, h);
            a2v = fmaf(h[q], av, a2v);
            d2v = fmaf(g[q], av, d2v);
        }
        a2buf[p] = a2v;
        d2out[p] = d2v;
    } else if (tid < 18) {
        // d1 groups {0,1,2,1023,1024} (d1[0..11], d1[4092..4098])
        const int j = (tid == 16) ? 1023 : ((tid == 17) ? 1024 : (tid - 13));
#pragma unroll 4
        for (int r = 0; r < 4; ++r) {
            const int pos = 4 * j + r;
            if (pos >= L1n) break;
            const int s0 = 2 * pos + 1;
            float d = 0.f;
#pragma unroll
            for (int q = 0; q < 8; ++q)
                d = fmaf(g[q], refl_load(xr, s0 - q, N0), d);
            d1out[pos] = d;
        }
    }
    __syncthreads();

    // L3: a2buf -> a3buf, d3 -> global
    dwt_level(a2buf, L2n, L3n, h, g, a3buf,
              out + OFF_D3 + (size_t)row * L3n, tid);
    __syncthreads();
    // L4: a3buf -> a2buf (a2 dead), d4 -> global
    dwt_level(a3buf, L3n, L4n, h, g, a2buf,
              out + OFF_D4 + (size_t)row * L4n, tid);
    __syncthreads();
    // L5: a2buf(a4) -> approx & d5 straight to global
    dwt_level(a2buf, L4n, L5n, h, g,
              out + (size_t)row * L5n,
              out + OFF_D5 + (size_t)row * L5n, tid);
}

extern "C" void kernel_launch(void* const* d_in, const int* in_sizes, int n_in,
                              void* d_out, int out_size, void* d_ws, size_t ws_size,
                              hipStream_t stream) {
    const float* x   = (const float*)d_in[0];
    const float* dlo = (const float*)d_in[1];
    const float* dhi = (const float*)d_in[2];
    float* out = (float*)d_out;
    wavedec5_fused<<<ROWS, 256, 0, stream>>>(x, dlo, dhi, out);
}

// Round 9
// 61.995 us; speedup vs baseline: 1.2717x; 1.2717x over previous
//
#include <hip/hip_runtime.h>

// 5-level wavedec (filter len 8, pywt 'symmetric'), 4096 rows of 8192 f32.
// Lengths: 8192 -> 4099 -> 2053 -> 1030 -> 518 -> 262
// Out: approx(262) @0, d5(262), d4(518), d3(1030), d2(2053), d1(4099).
//
// R9 = R3 structure + explicit 1-deep software pipeline per level (prefetch
// next window into regs while computing current -> hides LDS/global load
// latency under the 64-FMA block; R3's VGPR=40 showed the compiler wasn't
// doing this) + nontemporal global stores (write-once data, skip L2).

static constexpr int ROWS = 4096;
static constexpr int N0 = 8192;
static constexpr int L1n = 4099, L2n = 2053, L3n = 1030, L4n = 518, L5n = 262;
static constexpr size_t OFF_D5 = 1073152u;
static constexpr size_t OFF_D4 = 2146304u;
static constexpr size_t OFF_D3 = 4268032u;
static constexpr size_t OFF_D2 = 8486912u;
static constexpr size_t OFF_D1 = 16896000u;

__device__ __forceinline__ float refl_load(const float* __restrict__ s, int idx, int n) {
    int i = (idx < 0) ? (-1 - idx) : ((idx >= n) ? (2 * n - 1 - idx) : idx);
    return s[i];
}

// Load the 16-float window for group j (clamped to a safe interior base;
// edge groups discard this data and take the branchy path).
template <typename SRC>
__device__ __forceinline__ void load_window(const SRC* __restrict__ src,
                                            int j, int jmax, float* __restrict__ w) {
    int jb = j < 1 ? 1 : (j > jmax ? jmax : j);
    const float2* __restrict__ s2 = reinterpret_cast<const float2*>(src) + (4 * jb - 3);
#pragma unroll
    for (int t = 0; t < 8; ++t) {
        const float2 v = s2[t];
        w[2 * t] = v.x; w[2 * t + 1] = v.y;
    }
}

// One DWT level, 4 outputs/thread, 1-deep software pipeline.
template <bool LAST>
__device__ __forceinline__ void dwt_level(
    const float* __restrict__ src, int n, int m,
    const float* __restrict__ h, const float* __restrict__ g,
    float* __restrict__ adst, float* __restrict__ ddst, int tid)
{
    const int ngroups = (m + 3) >> 2;
    const int jmax = (n - 10) >> 3;   // interior iff 1 <= j <= jmax

    float wc[16], wn[16];
    int j = tid;
    if (j < ngroups) load_window(src, j, jmax, wc);
    while (j < ngroups) {
        const int jn = j + 256;
        if (jn < ngroups) load_window(src, jn, jmax, wn);  // prefetch next

        const int p0 = 4 * j;
        if (j >= 1 && j <= jmax && p0 + 3 < m) {
            float aa[4], dd[4];
#pragma unroll
            for (int r = 0; r < 4; ++r) {
                float a = 0.f, d = 0.f;
#pragma unroll
                for (int q = 0; q < 8; ++q) {
                    const float v = wc[2 * r + 7 - q];   // src[2(p0+r)+1-q]
                    a = fmaf(h[q], v, a);
                    d = fmaf(g[q], v, d);
                }
                aa[r] = a; dd[r] = d;
            }
#pragma unroll
            for (int r = 0; r < 4; ++r)
                __builtin_nontemporal_store(dd[r], ddst + p0 + r);
            if (LAST) {
#pragma unroll
                for (int r = 0; r < 4; ++r)
                    __builtin_nontemporal_store(aa[r], adst + p0 + r);
            } else {
#pragma unroll
                for (int r = 0; r < 4; ++r) adst[p0 + r] = aa[r];
            }
        } else {
            // edge groups: branchy symmetric-reflect path (2-3 per level)
#pragma unroll 4
            for (int r = 0; r < 4; ++r) {
                const int pos = p0 + r;
                if (pos >= m) break;
                const int s0 = 2 * pos + 1;
                float a = 0.f, d = 0.f;
#pragma unroll
                for (int q = 0; q < 8; ++q) {
                    const float v = refl_load(src, s0 - q, n);
                    a = fmaf(h[q], v, a);
                    d = fmaf(g[q], v, d);
                }
                ddst[pos] = d;
                adst[pos] = a;
            }
        }
        j = jn;
#pragma unroll
        for (int t = 0; t < 16; ++t) wc[t] = wn[t];
    }
}

__global__ __launch_bounds__(256, 6)
void wavedec5_kernel(const float* __restrict__ x,
                     const float* __restrict__ dlo,
                     const float* __restrict__ dhi,
                     float* __restrict__ out)
{
    __shared__ __align__(16) float bufA[4100];  // a1 / a3
    __shared__ __align__(16) float bufB[2056];  // a2 / a4

    const int row = blockIdx.x;
    const int tid = threadIdx.x;

    float h[8], g[8];
#pragma unroll
    for (int i = 0; i < 8; ++i) { h[i] = dlo[i]; g[i] = dhi[i]; }

    const float* __restrict__ xr = x + (size_t)row * N0;

    // L1: global -> bufA, d1 -> global
    dwt_level<false>(xr, N0, L1n, h, g, bufA,
                     out + OFF_D1 + (size_t)row * L1n, tid);
    __syncthreads();
    // L2: bufA -> bufB, d2 -> global
    dwt_level<false>(bufA, L1n, L2n, h, g, bufB,
                     out + OFF_D2 + (size_t)row * L2n, tid);
    __syncthreads();
    // L3: bufB -> bufA, d3 -> global
    dwt_level<false>(bufB, L2n, L3n, h, g, bufA,
                     out + OFF_D3 + (size_t)row * L3n, tid);
    __syncthreads();
    // L4: bufA -> bufB, d4 -> global
    dwt_level<false>(bufA, L3n, L4n, h, g, bufB,
                     out + OFF_D4 + (size_t)row * L4n, tid);
    __syncthreads();
    // L5: bufB -> approx & d5 straight to global
    dwt_level<true>(bufB, L4n, L5n, h, g,
                    out + (size_t)row * L5n,
                    out + OFF_D5 + (size_t)row * L5n, tid);
}

extern "C" void kernel_launch(void* const* d_in, const int* in_sizes, int n_in,
                              void* d_out, int out_size, void* d_ws, size_t ws_size,
                              hipStream_t stream) {
    const float* x   = (const float*)d_in[0];
    const float* dlo = (const float*)d_in[1];
    const float* dhi = (const float*)d_in[2];
    float* out = (float*)d_out;
    wavedec5_kernel<<<ROWS, 256, 0, stream>>>(x, dlo, dhi, out);
}

// Round 10
// 58.398 us; speedup vs baseline: 1.3500x; 1.0616x over previous
//
#include <hip/hip_runtime.h>

// 5-level wavedec (filter len 8, pywt 'symmetric'), 4096 rows of 8192 f32.
// Lengths: 8192 -> 4099 -> 2053 -> 1030 -> 518 -> 262
// Out: approx(262) @0, d5(262), d4(518), d3(1030), d2(2053), d1(4099).
//
// R10: all level geometry is constexpr (template<N,M,NITER>). Each level
// loads ALL its windows upfront into registers (L1: 4x16 floats, L2: 2x16,
// L3-5: 1x16) with sched_barrier(0) pinning loads before compute -> one
// latency exposure per level instead of per iteration. R3/R9's VGPR=40
// proved the compiler never pipelines this on its own.

static constexpr int ROWS = 4096;
static constexpr int N0 = 8192;
static constexpr int L1n = 4099, L2n = 2053, L3n = 1030, L4n = 518, L5n = 262;
static constexpr size_t OFF_D5 = 1073152u;
static constexpr size_t OFF_D4 = 2146304u;
static constexpr size_t OFF_D3 = 4268032u;
static constexpr size_t OFF_D2 = 8486912u;
static constexpr size_t OFF_D1 = 16896000u;

__device__ __forceinline__ float refl_load(const float* __restrict__ s, int idx, int n) {
    int i = (idx < 0) ? (-1 - idx) : ((idx >= n) ? (2 * n - 1 - idx) : idx);
    return s[i];
}

// Clamped 16-float window load for group j: w[t] = src[8j-6+t]
template <int N>
__device__ __forceinline__ void load_window(const float* __restrict__ src,
                                            int j, float* __restrict__ w) {
    constexpr int jmax = (N - 10) >> 3;
    const int jb = j < 1 ? 1 : (j > jmax ? jmax : j);
    const float2* __restrict__ s2 = reinterpret_cast<const float2*>(src) + (4 * jb - 3);
#pragma unroll
    for (int t = 0; t < 8; ++t) {
        const float2 v = s2[t];
        w[2 * t] = v.x; w[2 * t + 1] = v.y;
    }
}

// Branchy symmetric-reflect path for edge / partial groups.
template <int N, int M>
__device__ __forceinline__ void edge_group(
    const float* __restrict__ src,
    const float* __restrict__ h, const float* __restrict__ g,
    float* __restrict__ adst, float* __restrict__ ddst, int j)
{
#pragma unroll 4
    for (int r = 0; r < 4; ++r) {
        const int pos = 4 * j + r;
        if (pos >= M) break;
        const int s0 = 2 * pos + 1;
        float a = 0.f, d = 0.f;
#pragma unroll
        for (int q = 0; q < 8; ++q) {
            const float v = refl_load(src, s0 - q, N);
            a = fmaf(h[q], v, a);
            d = fmaf(g[q], v, d);
        }
        ddst[pos] = d;
        adst[pos] = a;
    }
}

// One DWT level, all NITER windows loaded upfront (register-resident MLP).
template <int N, int M, int NITER>
__device__ __forceinline__ void dwt_level(
    const float* __restrict__ src,
    const float* __restrict__ h, const float* __restrict__ g,
    float* __restrict__ adst, float* __restrict__ ddst, int tid)
{
    constexpr int ngroups = (M + 3) >> 2;
    constexpr int jmax = (N - 10) >> 3;
    constexpr int rem = ngroups - NITER * 256;   // leftover (edge) groups
    constexpr bool full = (NITER * 256 <= ngroups);  // all t-slots valid

    float w[NITER][16];
#pragma unroll
    for (int t = 0; t < NITER; ++t) {
        const int j = tid + t * 256;
        if (full || j < ngroups)
            load_window<N>(src, j, &w[t][0]);
    }
    __builtin_amdgcn_sched_barrier(0);   // pin: all loads issued before compute

#pragma unroll
    for (int t = 0; t < NITER; ++t) {
        const int j = tid + t * 256;
        if (!full && j >= ngroups) break;
        const int p0 = 4 * j;
        if (j >= 1 && j <= jmax && p0 + 3 < M) {
            float aa[4], dd[4];
#pragma unroll
            for (int r = 0; r < 4; ++r) {
                float a = 0.f, d = 0.f;
#pragma unroll
                for (int q = 0; q < 8; ++q) {
                    const float v = w[t][2 * r + 7 - q];   // src[2(p0+r)+1-q]
                    a = fmaf(h[q], v, a);
                    d = fmaf(g[q], v, d);
                }
                aa[r] = a; dd[r] = d;
            }
#pragma unroll
            for (int r = 0; r < 4; ++r) ddst[p0 + r] = dd[r];
#pragma unroll
            for (int r = 0; r < 4; ++r) adst[p0 + r] = aa[r];
        } else {
            edge_group<N, M>(src, h, g, adst, ddst, j);
        }
    }
    if constexpr (rem > 0) {
        if (tid < rem)
            edge_group<N, M>(src, h, g, adst, ddst, NITER * 256 + tid);
    }
}

__global__ __launch_bounds__(256, 4)
void wavedec5_kernel(const float* __restrict__ x,
                     const float* __restrict__ dlo,
                     const float* __restrict__ dhi,
                     float* __restrict__ out)
{
    __shared__ __align__(16) float bufA[4100];  // a1 / a3
    __shared__ __align__(16) float bufB[2056];  // a2 / a4

    const int row = blockIdx.x;
    const int tid = threadIdx.x;

    float h[8], g[8];
#pragma unroll
    for (int i = 0; i < 8; ++i) { h[i] = dlo[i]; g[i] = dhi[i]; }

    const float* __restrict__ xr = x + (size_t)row * N0;

    // L1: global -> bufA, d1 -> global  (4 windows upfront = 32 global loads in flight)
    dwt_level<N0, L1n, 4>(xr, h, g, bufA,
                          out + OFF_D1 + (size_t)row * L1n, tid);
    __syncthreads();
    // L2: bufA -> bufB, d2 -> global  (2 windows upfront)
    dwt_level<L1n, L2n, 2>(bufA, h, g, bufB,
                           out + OFF_D2 + (size_t)row * L2n, tid);
    __syncthreads();
    // L3: bufB -> bufA, d3 -> global
    dwt_level<L2n, L3n, 1>(bufB, h, g, bufA,
                           out + OFF_D3 + (size_t)row * L3n, tid);
    __syncthreads();
    // L4: bufA -> bufB, d4 -> global
    dwt_level<L3n, L4n, 1>(bufA, h, g, bufB,
                           out + OFF_D4 + (size_t)row * L4n, tid);
    __syncthreads();
    // L5: bufB -> approx & d5 straight to global
    dwt_level<L4n, L5n, 1>(bufB, h, g,
                           out + (size_t)row * L5n,
                           out + OFF_D5 + (size_t)row * L5n, tid);
}

extern "C" void kernel_launch(void* const* d_in, const int* in_sizes, int n_in,
                              void* d_out, int out_size, void* d_ws, size_t ws_size,
                              hipStream_t stream) {
    const float* x   = (const float*)d_in[0];
    const float* dlo = (const float*)d_in[1];
    const float* dhi = (const float*)d_in[2];
    float* out = (float*)d_out;
    wavedec5_kernel<<<ROWS, 256, 0, stream>>>(x, dlo, dhi, out);
}